// Round 1
// baseline (394.450 us; speedup 1.0000x reference)
//
#include <hip/hip_runtime.h>
#include <stdint.h>

typedef __attribute__((ext_vector_type(4))) float floatx4;
typedef __attribute__((ext_vector_type(8))) short shortx8;

#define EPSF 1e-5f

// round-to-nearest-even fp32 -> bf16
__device__ __forceinline__ unsigned short f2bf(float f) {
    union { float f; unsigned int u; } v;
    v.f = f;
    unsigned int u = v.u;
    u += 0x7fffu + ((u >> 16) & 1u);
    return (unsigned short)(u >> 16);
}

// ---------------------------------------------------------------------------
// Phase 1: per-head inverse.  A = (1+eps)I + (S_raw - S_raw^T).
// Since B = I - S = (2+eps)I - A commutes with A^-1:
//   M = B A^-1 = (2+eps) A^-1 - I.
// In-place Gauss-Jordan without pivoting (A's symmetric part is (1+eps)I > 0,
// so all leading minors are nonzero).  One block of 1024 threads per head;
// thread (i = t>>3, s = t&7) owns row i, cols [16s,16s+16) in registers.
// Pivot row/column round-trip through double-buffered LDS: 1 barrier/step.
// ---------------------------------------------------------------------------
__global__ __launch_bounds__(1024) void cayley_invert(
    const float* __restrict__ S_raw, unsigned short* __restrict__ Mb)
{
    const int h  = blockIdx.x;
    const int t  = threadIdx.x;
    const int i  = t >> 3;     // row 0..127
    const int s  = t & 7;      // col segment 0..7
    const int j0 = s * 16;
    const float* Sr = S_raw + (size_t)h * 16384;

    float loc[16];
#pragma unroll
    for (int m = 0; m < 16; ++m) {
        const int j = j0 + m;
        float v = Sr[i * 128 + j] - Sr[j * 128 + i];
        if (i == j) v += 1.0f + EPSF;
        loc[m] = v;
    }

    __shared__ __align__(16) float rowbuf[2][128];  // raw pivot row k
    __shared__ float dumbuf[2][128];                // raw pivot column k

    if (i == 0) {
#pragma unroll
        for (int m = 0; m < 16; ++m) rowbuf[0][j0 + m] = loc[m];
    }
    if (s == 0) dumbuf[0][i] = loc[0];
    __syncthreads();

    for (int k = 0; k < 128; ++k) {
        const int cur = k & 1, nxt = cur ^ 1;
        const float pivinv = 1.0f / rowbuf[cur][k];
        const float dum    = dumbuf[cur][i];

        floatx4 rv[4];
#pragma unroll
        for (int q = 0; q < 4; ++q)
            rv[q] = *(const floatx4*)(&rowbuf[cur][j0 + q * 4]);

        const int kn = k + 1;
        float dv = 0.0f;
        const bool isPivRow = (i == k);
#pragma unroll
        for (int m = 0; m < 16; ++m) {
            const int j = j0 + m;
            const float rs   = (j == k) ? pivinv : rv[m >> 2][m & 3] * pivinv;
            const float base = (j == k) ? 0.0f   : loc[m];
            const float nv   = isPivRow ? rs : fmaf(-dum, rs, base);
            loc[m] = nv;
            dv = (j == kn) ? nv : dv;   // next step's column value (if owned)
        }

        if (kn < 128) {
            if (i == kn) {              // publish next pivot row (raw)
#pragma unroll
                for (int q = 0; q < 4; ++q) {
                    floatx4 w;
                    w[0] = loc[q * 4 + 0]; w[1] = loc[q * 4 + 1];
                    w[2] = loc[q * 4 + 2]; w[3] = loc[q * 4 + 3];
                    *(floatx4*)(&rowbuf[nxt][j0 + q * 4]) = w;
                }
            }
            if ((kn >> 4) == s) dumbuf[nxt][i] = dv;  // publish next pivot col
        }
        __syncthreads();
    }

    // M = (2+eps)*Ainv - I  -> bf16
    unsigned short* dst = Mb + (size_t)h * 16384 + i * 128 + j0;
    shortx8 o0, o1;
#pragma unroll
    for (int m = 0; m < 16; ++m) {
        const int j = j0 + m;
        const float v = (2.0f + EPSF) * loc[m] - ((i == j) ? 1.0f : 0.0f);
        const unsigned short b = f2bf(v);
        if (m < 8) o0[m] = (short)b; else o1[m - 8] = (short)b;
    }
    *(shortx8*)(dst)     = o0;
    *(shortx8*)(dst + 8) = o1;
}

// ---------------------------------------------------------------------------
// Phase 2: y[b,h,n,d] = sum_k M_h[d,k] * x[b,h,n,k].
// Per-head GEMM: (16384 rows x 128) x M_h^T, bf16 MFMA 16x16x32, fp32 acc.
// M is the A operand (A[m=lane&15][k=quad*8+j]) so D rows = d:
//   D[m = quad*4+reg -> d][n = lane&15 -> x-row]  => contiguous-d float4 store.
// Block = 256 thr (4 waves), each block: 128 x-rows, all 128 d-cols.
// M_h staged in LDS, stride padded 128->136 bf16 to break bank conflicts.
// ---------------------------------------------------------------------------
__global__ __launch_bounds__(256) void cayley_apply(
    const float* __restrict__ x, const unsigned short* __restrict__ Mb,
    float* __restrict__ y)
{
    const int bid   = blockIdx.x;
    const int bh    = bid >> 5;        // b*16 + h, 0..63
    const int ntile = bid & 31;        // 128-row tile within (b,h)
    const int h     = bh & 15;
    const int tid   = threadIdx.x;
    const int w     = tid >> 6;
    const int lane  = tid & 63;
    const int l15   = lane & 15;
    const int quad  = lane >> 4;

    __shared__ __align__(16) unsigned short Msh[128 * 136];

    {   // stage M_h (32 KB bf16) into LDS
        const unsigned short* Mg = Mb + (size_t)h * 16384;
#pragma unroll
        for (int it = 0; it < 8; ++it) {
            const int c   = tid + it * 256;   // 2048 chunks of 8 ushorts
            const int row = c >> 4;
            const int cc  = (c & 15) * 8;
            const shortx8 v = *(const shortx8*)(Mg + row * 128 + cc);
            *(shortx8*)(&Msh[row * 136 + cc]) = v;
        }
    }
    __syncthreads();

    const size_t base   = (size_t)bh * (4096 * 128);
    const int rowbase   = ntile * 128 + w * 32;

    floatx4 acc[2][8];
#pragma unroll
    for (int mt = 0; mt < 2; ++mt)
#pragma unroll
        for (int ct = 0; ct < 8; ++ct) acc[mt][ct] = (floatx4)0.0f;

#pragma unroll
    for (int ks = 0; ks < 4; ++ks) {
        const int koff = ks * 32 + quad * 8;

        shortx8 xf[2];   // x rows as B operand
#pragma unroll
        for (int mt = 0; mt < 2; ++mt) {
            const float* xp = x + base + (size_t)(rowbase + mt * 16 + l15) * 128 + koff;
            const floatx4 a = *(const floatx4*)xp;
            const floatx4 b = *(const floatx4*)(xp + 4);
            shortx8 f;
            f[0] = (short)f2bf(a[0]); f[1] = (short)f2bf(a[1]);
            f[2] = (short)f2bf(a[2]); f[3] = (short)f2bf(a[3]);
            f[4] = (short)f2bf(b[0]); f[5] = (short)f2bf(b[1]);
            f[6] = (short)f2bf(b[2]); f[7] = (short)f2bf(b[3]);
            xf[mt] = f;
        }

#pragma unroll
        for (int ct = 0; ct < 8; ++ct) {
            const int d = ct * 16 + l15;
            const shortx8 mf = *(const shortx8*)(&Msh[d * 136 + koff]);
            acc[0][ct] = __builtin_amdgcn_mfma_f32_16x16x32_bf16(mf, xf[0], acc[0][ct], 0, 0, 0);
            acc[1][ct] = __builtin_amdgcn_mfma_f32_16x16x32_bf16(mf, xf[1], acc[1][ct], 0, 0, 0);
        }
    }

    // D[m=quad*4+r -> d][n=l15 -> row]: float4 store over consecutive d
#pragma unroll
    for (int mt = 0; mt < 2; ++mt) {
        const int row = rowbase + mt * 16 + l15;
        float* yr = y + base + (size_t)row * 128;
#pragma unroll
        for (int ct = 0; ct < 8; ++ct)
            *(floatx4*)(yr + ct * 16 + quad * 4) = acc[mt][ct];
    }
}

extern "C" void kernel_launch(void* const* d_in, const int* in_sizes, int n_in,
                              void* d_out, int out_size, void* d_ws, size_t ws_size,
                              hipStream_t stream) {
    const float* x     = (const float*)d_in[0];   // (4,16,4096,128) fp32
    const float* S_raw = (const float*)d_in[1];   // (16,128,128) fp32
    float* y = (float*)d_out;                     // (4,16,4096,128) fp32
    unsigned short* Mb = (unsigned short*)d_ws;   // 16*128*128 bf16 = 512 KB

    cayley_invert<<<16, 1024, 0, stream>>>(S_raw, Mb);
    cayley_apply<<<64 * 32, 256, 0, stream>>>(x, Mb, y);
}

// Round 2
// 320.072 us; speedup vs baseline: 1.2324x; 1.2324x over previous
//
#include <hip/hip_runtime.h>
#include <stdint.h>

typedef __attribute__((ext_vector_type(4))) float floatx4;
typedef __attribute__((ext_vector_type(8))) short shortx8;
typedef __attribute__((ext_vector_type(2))) __bf16 bf16x2;

#define EPSF 1e-5f

#if defined(__has_builtin)
#if __has_builtin(__builtin_amdgcn_cvt_pk_bf16_f32)
#define HAVE_CVT_PK_BF16 1
#endif
#if __has_builtin(__builtin_amdgcn_rcpf)
#define HAVE_RCPF 1
#endif
#endif

// pack two fp32 -> packed bf16x2 (RNE)
__device__ __forceinline__ unsigned int pack2_bf16(float a, float b) {
#ifdef HAVE_CVT_PK_BF16
    bf16x2 r = __builtin_amdgcn_cvt_pk_bf16_f32(a, b);
    union { bf16x2 v; unsigned int u; } cv; cv.v = r; return cv.u;
#else
    unsigned int ua = __float_as_uint(a), ub = __float_as_uint(b);
    ua = (ua + 0x7fffu + ((ua >> 16) & 1u)) >> 16;
    ub = (ub + 0x7fffu + ((ub >> 16) & 1u)) & 0xffff0000u;
    return ub | ua;
#endif
}

__device__ __forceinline__ float fast_rcp(float x) {
#ifdef HAVE_RCPF
    return __builtin_amdgcn_rcpf(x);   // ~1 ulp, fine: output is bf16
#else
    return 1.0f / x;
#endif
}

// ---------------------------------------------------------------------------
// Phase 1: per-head M = (2+eps)*A^-1 - I,  A = (1+eps)I + (S_raw - S_raw^T).
// Gauss-Jordan without pivoting as a BRANCHLESS uniform rank-1 update:
// publish pivot row w with w_k = a_kk + 1, pivot col dum with dum_k = a_kk - 1;
// then for ALL (i,j): new[i][j] = a[i][j] - (dum_i / a_kk) * w_j.
//   (i!=k,j!=k): standard;  (k,j): a_kj/a_kk;  (i,k): -a_ik/a_kk;  (k,k): 1/a_kk.
// 512 thr/block (8 waves): thread (i=t>>2, s=t&3) owns 32 cols of row i in regs.
// k-loop split 4 x unroll(32) so the next-pivot-col register index is STATIC.
// Double-buffered LDS row/col: one barrier per step.
// ---------------------------------------------------------------------------
__global__ __launch_bounds__(512) void cayley_invert(
    const float* __restrict__ S_raw, unsigned short* __restrict__ Mb)
{
    const int h  = blockIdx.x;
    const int t  = threadIdx.x;
    const int i  = t >> 2;      // row 0..127
    const int s  = t & 3;       // col segment 0..3
    const int j0 = s << 5;      // 32 cols per thread
    const float* Sr = S_raw + (size_t)h * 16384;

    float loc[32];
#pragma unroll
    for (int m = 0; m < 32; ++m) {
        const int j = j0 + m;
        float v = Sr[i * 128 + j] - Sr[j * 128 + i];
        if (j == i) v += 1.0f + EPSF;
        loc[m] = v;
    }

    __shared__ __align__(16) float rowbuf[2][128];  // w vector (adjusted)
    __shared__ float dumbuf[2][128];                // dum vector (adjusted)

    // initial publish for k=0
    if (i == 0) {
#pragma unroll
        for (int q = 0; q < 8; ++q) {
            floatx4 w;
            w[0] = loc[q*4+0]; w[1] = loc[q*4+1]; w[2] = loc[q*4+2]; w[3] = loc[q*4+3];
            if (q == 0 && s == 0) w[0] += 1.0f;    // w_k = a_kk + 1
            *(floatx4*)(&rowbuf[0][j0 + q*4]) = w;
        }
    }
    if (s == 0) {
        float dv = loc[0];
        if (i == 0) dv -= 1.0f;                    // dum_k = a_kk - 1
        dumbuf[0][i] = dv;
    }
    __syncthreads();

    for (int kb = 0; kb < 4; ++kb) {
#pragma unroll
        for (int kk = 0; kk < 32; ++kk) {
            const int cur = kk & 1;                // k parity (kb*32 even)
            const int nxt = cur ^ 1;
            const int k   = (kb << 5) + kk;

            const float wk  = rowbuf[cur][k];      // broadcast
            const float dum = dumbuf[cur][i];
            const float akk = wk - 1.0f;
            const float de  = dum * fast_rcp(akk);

            floatx4 rv[8];
#pragma unroll
            for (int q = 0; q < 8; ++q)
                rv[q] = *(const floatx4*)(&rowbuf[cur][j0 + q*4]);

#pragma unroll
            for (int m = 0; m < 32; ++m)           // pure FMA, no selects
                loc[m] = fmaf(-de, rv[m >> 2][m & 3], loc[m]);

            const int kn = k + 1;
            if (kn < 128) {
                const int sp   = (kk == 31) ? kb + 1 : kb;  // seg owning col kn
                const int mloc = (kk == 31) ? 0 : kk + 1;   // STATIC reg index
                const int qm   = mloc >> 2, em = mloc & 3;  // static

                if (i == kn) {                     // publish next pivot row
#pragma unroll
                    for (int q = 0; q < 8; ++q) {
                        floatx4 w;
                        w[0] = loc[q*4+0]; w[1] = loc[q*4+1];
                        w[2] = loc[q*4+2]; w[3] = loc[q*4+3];
                        if (q == qm && s == sp) w[em] += 1.0f;
                        *(floatx4*)(&rowbuf[nxt][j0 + q*4]) = w;
                    }
                }
                if (s == sp) {                     // publish next pivot col
                    float dv = loc[mloc];
                    if (i == kn) dv -= 1.0f;
                    dumbuf[nxt][i] = dv;
                }
            }
            __syncthreads();
        }
    }

    // M = (2+eps)*Ainv - I  -> bf16
    unsigned short* dst = Mb + (size_t)h * 16384 + i * 128 + j0;
#pragma unroll
    for (int q = 0; q < 4; ++q) {
        union { shortx8 v; unsigned int u[4]; } cv;
#pragma unroll
        for (int p = 0; p < 4; ++p) {
            const int m = q*8 + p*2;
            const float v0 = (2.0f + EPSF) * loc[m]   - ((j0 + m   == i) ? 1.0f : 0.0f);
            const float v1 = (2.0f + EPSF) * loc[m+1] - ((j0 + m+1 == i) ? 1.0f : 0.0f);
            cv.u[p] = pack2_bf16(v0, v1);
        }
        *(shortx8*)(dst + q*8) = cv.v;
    }
}

// ---------------------------------------------------------------------------
// Phase 2: y[b,h,n,d] = sum_k M_h[d,k] * x[b,h,n,k].
// bf16 MFMA 16x16x32, M as A operand => D rows = d, contiguous-d float4 store.
// Block = 256 thr (4 waves): 128 x-rows, all 128 d. M_h in LDS (pad 128->136).
// ---------------------------------------------------------------------------
__global__ __launch_bounds__(256) void cayley_apply(
    const float* __restrict__ x, const unsigned short* __restrict__ Mb,
    float* __restrict__ y)
{
    const int bid   = blockIdx.x;
    const int bh    = bid >> 5;        // b*16 + h
    const int ntile = bid & 31;
    const int h     = bh & 15;
    const int tid   = threadIdx.x;
    const int w     = tid >> 6;
    const int lane  = tid & 63;
    const int l15   = lane & 15;
    const int quad  = lane >> 4;

    __shared__ __align__(16) unsigned short Msh[128 * 136];

    {   // stage M_h (32 KB bf16) into LDS
        const unsigned short* Mg = Mb + (size_t)h * 16384;
#pragma unroll
        for (int it = 0; it < 8; ++it) {
            const int c   = tid + it * 256;
            const int row = c >> 4;
            const int cc  = (c & 15) * 8;
            const shortx8 v = *(const shortx8*)(Mg + row * 128 + cc);
            *(shortx8*)(&Msh[row * 136 + cc]) = v;
        }
    }
    __syncthreads();

    const size_t base = (size_t)bh * (4096 * 128);
    const int rowbase = ntile * 128 + w * 32;

    floatx4 acc[2][8];
#pragma unroll
    for (int mt = 0; mt < 2; ++mt)
#pragma unroll
        for (int ct = 0; ct < 8; ++ct) acc[mt][ct] = (floatx4)0.0f;

#pragma unroll
    for (int ks = 0; ks < 4; ++ks) {
        const int koff = ks * 32 + quad * 8;

        shortx8 xf[2];
#pragma unroll
        for (int mt = 0; mt < 2; ++mt) {
            const float* xp = x + base + (size_t)(rowbase + mt * 16 + l15) * 128 + koff;
            const floatx4 a = *(const floatx4*)xp;
            const floatx4 b = *(const floatx4*)(xp + 4);
            union { shortx8 v; unsigned int u[4]; } cv;
            cv.u[0] = pack2_bf16(a[0], a[1]);
            cv.u[1] = pack2_bf16(a[2], a[3]);
            cv.u[2] = pack2_bf16(b[0], b[1]);
            cv.u[3] = pack2_bf16(b[2], b[3]);
            xf[mt] = cv.v;
        }

#pragma unroll
        for (int ct = 0; ct < 8; ++ct) {
            const int d = ct * 16 + l15;
            const shortx8 mf = *(const shortx8*)(&Msh[d * 136 + koff]);
            acc[0][ct] = __builtin_amdgcn_mfma_f32_16x16x32_bf16(mf, xf[0], acc[0][ct], 0, 0, 0);
            acc[1][ct] = __builtin_amdgcn_mfma_f32_16x16x32_bf16(mf, xf[1], acc[1][ct], 0, 0, 0);
        }
    }

#pragma unroll
    for (int mt = 0; mt < 2; ++mt) {
        const int row = rowbase + mt * 16 + l15;
        float* yr = y + base + (size_t)row * 128;
#pragma unroll
        for (int ct = 0; ct < 8; ++ct)
            *(floatx4*)(yr + ct * 16 + quad * 4) = acc[mt][ct];
    }
}

extern "C" void kernel_launch(void* const* d_in, const int* in_sizes, int n_in,
                              void* d_out, int out_size, void* d_ws, size_t ws_size,
                              hipStream_t stream) {
    const float* x     = (const float*)d_in[0];   // (4,16,4096,128) fp32
    const float* S_raw = (const float*)d_in[1];   // (16,128,128) fp32
    float* y = (float*)d_out;                     // (4,16,4096,128) fp32
    unsigned short* Mb = (unsigned short*)d_ws;   // 16*128*128 bf16 = 512 KB

    cayley_invert<<<16, 512, 0, stream>>>(S_raw, Mb);
    cayley_apply<<<64 * 32, 256, 0, stream>>>(x, Mb, y);
}

// Round 3
// 319.310 us; speedup vs baseline: 1.2353x; 1.0024x over previous
//
#include <hip/hip_runtime.h>
#include <stdint.h>

typedef __attribute__((ext_vector_type(4))) float floatx4;
typedef __attribute__((ext_vector_type(8))) short shortx8;
typedef __attribute__((ext_vector_type(2))) __bf16 bf16x2;

#define EPSF 1e-5f

#if defined(__has_builtin)
#if __has_builtin(__builtin_amdgcn_cvt_pk_bf16_f32)
#define HAVE_CVT_PK_BF16 1
#endif
#if __has_builtin(__builtin_amdgcn_rcpf)
#define HAVE_RCPF 1
#endif
#endif

// pack two fp32 -> packed bf16x2 (RNE)
__device__ __forceinline__ unsigned int pack2_bf16(float a, float b) {
#ifdef HAVE_CVT_PK_BF16
    bf16x2 r = __builtin_amdgcn_cvt_pk_bf16_f32(a, b);
    union { bf16x2 v; unsigned int u; } cv; cv.v = r; return cv.u;
#else
    unsigned int ua = __float_as_uint(a), ub = __float_as_uint(b);
    ua = (ua + 0x7fffu + ((ua >> 16) & 1u)) >> 16;
    ub = (ub + 0x7fffu + ((ub >> 16) & 1u)) & 0xffff0000u;
    return ub | ua;
#endif
}

__device__ __forceinline__ float fast_rcp(float x) {
#ifdef HAVE_RCPF
    return __builtin_amdgcn_rcpf(x);   // ~1 ulp, fine: output is bf16
#else
    return 1.0f / x;
#endif
}

// ---------------------------------------------------------------------------
// Phase 1: per-head M = (2+eps)*A^-1 - I,  A = (1+eps)I + (S_raw - S_raw^T).
// Branchless Gauss-Jordan (no pivoting; symmetric part (1+eps)I > 0).
// Publish pivot row w (w_k = a_kk+1) and col dum (dum_k = a_kk-1); then for
// ALL (i,j): new = a - (dum_i/a_kk)*w_j.  512 thr: thread (i=t>>2,s=t&3)
// owns 32 cols of row i in regs.  k-loop 4 x unroll(32) -> static reg idx.
// UNCHANGED from round 2 (known-good, ~89 us) — next round's target.
// ---------------------------------------------------------------------------
__global__ __launch_bounds__(512) void cayley_invert(
    const float* __restrict__ S_raw, unsigned short* __restrict__ Mb)
{
    const int h  = blockIdx.x;
    const int t  = threadIdx.x;
    const int i  = t >> 2;      // row 0..127
    const int s  = t & 3;       // col segment 0..3
    const int j0 = s << 5;      // 32 cols per thread
    const float* Sr = S_raw + (size_t)h * 16384;

    float loc[32];
#pragma unroll
    for (int m = 0; m < 32; ++m) {
        const int j = j0 + m;
        float v = Sr[i * 128 + j] - Sr[j * 128 + i];
        if (j == i) v += 1.0f + EPSF;
        loc[m] = v;
    }

    __shared__ __align__(16) float rowbuf[2][128];
    __shared__ float dumbuf[2][128];

    if (i == 0) {
#pragma unroll
        for (int q = 0; q < 8; ++q) {
            floatx4 w;
            w[0] = loc[q*4+0]; w[1] = loc[q*4+1]; w[2] = loc[q*4+2]; w[3] = loc[q*4+3];
            if (q == 0 && s == 0) w[0] += 1.0f;
            *(floatx4*)(&rowbuf[0][j0 + q*4]) = w;
        }
    }
    if (s == 0) {
        float dv = loc[0];
        if (i == 0) dv -= 1.0f;
        dumbuf[0][i] = dv;
    }
    __syncthreads();

    for (int kb = 0; kb < 4; ++kb) {
#pragma unroll
        for (int kk = 0; kk < 32; ++kk) {
            const int cur = kk & 1;
            const int nxt = cur ^ 1;
            const int k   = (kb << 5) + kk;

            const float wk  = rowbuf[cur][k];
            const float dum = dumbuf[cur][i];
            const float akk = wk - 1.0f;
            const float de  = dum * fast_rcp(akk);

            floatx4 rv[8];
#pragma unroll
            for (int q = 0; q < 8; ++q)
                rv[q] = *(const floatx4*)(&rowbuf[cur][j0 + q*4]);

#pragma unroll
            for (int m = 0; m < 32; ++m)
                loc[m] = fmaf(-de, rv[m >> 2][m & 3], loc[m]);

            const int kn = k + 1;
            if (kn < 128) {
                const int sp   = (kk == 31) ? kb + 1 : kb;
                const int mloc = (kk == 31) ? 0 : kk + 1;
                const int qm   = mloc >> 2, em = mloc & 3;

                if (i == kn) {
#pragma unroll
                    for (int q = 0; q < 8; ++q) {
                        floatx4 w;
                        w[0] = loc[q*4+0]; w[1] = loc[q*4+1];
                        w[2] = loc[q*4+2]; w[3] = loc[q*4+3];
                        if (q == qm && s == sp) w[em] += 1.0f;
                        *(floatx4*)(&rowbuf[nxt][j0 + q*4]) = w;
                    }
                }
                if (s == sp) {
                    float dv = loc[mloc];
                    if (i == kn) dv -= 1.0f;
                    dumbuf[nxt][i] = dv;
                }
            }
            __syncthreads();
        }
    }

    unsigned short* dst = Mb + (size_t)h * 16384 + i * 128 + j0;
#pragma unroll
    for (int q = 0; q < 4; ++q) {
        union { shortx8 v; unsigned int u[4]; } cv;
#pragma unroll
        for (int p = 0; p < 4; ++p) {
            const int m = q*8 + p*2;
            const float v0 = (2.0f + EPSF) * loc[m]   - ((j0 + m   == i) ? 1.0f : 0.0f);
            const float v1 = (2.0f + EPSF) * loc[m+1] - ((j0 + m+1 == i) ? 1.0f : 0.0f);
            cv.u[p] = pack2_bf16(v0, v1);
        }
        *(shortx8*)(dst + q*8) = cv.v;
    }
}

// ---------------------------------------------------------------------------
// Phase 2: y[b,h,n,d] = sum_k M_h[d,k] * x[b,h,n,k].  bf16 MFMA 16x16x32,
// M as A operand (D rows = d).  v3: 512 blocks x 256 thr; each wave owns 128
// rows as 8 pipelined 16-row tiles (double-buffered x prefetch).  Output is
// transposed through a per-wave LDS buffer (two 64-d halves, 68-float pad)
// and stored as 256-B-contiguous nontemporal dwordx4 runs (vs 64-B scatter
// in v2 -> theory: writes were the 91-us limiter).
// ---------------------------------------------------------------------------
__global__ __launch_bounds__(256) void cayley_apply(
    const float* __restrict__ x, const unsigned short* __restrict__ Mb,
    float* __restrict__ y)
{
    const int bid  = blockIdx.x;       // 512 blocks
    const int bh   = bid >> 3;         // b*16+h, 0..63
    const int g    = bid & 7;          // 512-row group
    const int h    = bh & 15;
    const int tid  = threadIdx.x;
    const int w    = tid >> 6;
    const int lane = tid & 63;
    const int l15  = lane & 15;
    const int quad = lane >> 4;

    __shared__ __align__(16) unsigned short Msh[128 * 136];  // 34816 B
    __shared__ __align__(16) float obuf[4 * 16 * 68];        // 17408 B

    {   // stage M_h once per block
        const unsigned short* Mg = Mb + (size_t)h * 16384;
#pragma unroll
        for (int it = 0; it < 8; ++it) {
            const int c   = tid + it * 256;
            const int row = c >> 4;
            const int cc  = (c & 15) * 8;
            *(shortx8*)(&Msh[row * 136 + cc]) = *(const shortx8*)(Mg + row * 128 + cc);
        }
    }
    __syncthreads();

    const size_t base = (size_t)bh * (4096 * 128);
    const int row0    = g * 512 + w * 128;               // wave's first row
    const float* xw   = x + base + (size_t)(row0 + l15) * 128;
    float* ob         = obuf + w * (16 * 68);            // per-wave region

    floatx4 xa[2][8];
    // prefetch tile 0
#pragma unroll
    for (int ks = 0; ks < 4; ++ks) {
        xa[0][ks*2+0] = *(const floatx4*)(xw + ks*32 + quad*8);
        xa[0][ks*2+1] = *(const floatx4*)(xw + ks*32 + quad*8 + 4);
    }

#pragma unroll
    for (int t = 0; t < 8; ++t) {
        const int cur = t & 1, nxt = cur ^ 1;
        if (t < 7) {   // prefetch tile t+1 (compile-time guard)
            const float* xn = xw + (size_t)(t + 1) * (16 * 128);
#pragma unroll
            for (int ks = 0; ks < 4; ++ks) {
                xa[nxt][ks*2+0] = *(const floatx4*)(xn + ks*32 + quad*8);
                xa[nxt][ks*2+1] = *(const floatx4*)(xn + ks*32 + quad*8 + 4);
            }
        }

        shortx8 xf[4];
#pragma unroll
        for (int ks = 0; ks < 4; ++ks) {
            const floatx4 a = xa[cur][ks*2+0];
            const floatx4 b = xa[cur][ks*2+1];
            union { shortx8 v; unsigned int u[4]; } cv;
            cv.u[0] = pack2_bf16(a[0], a[1]);
            cv.u[1] = pack2_bf16(a[2], a[3]);
            cv.u[2] = pack2_bf16(b[0], b[1]);
            cv.u[3] = pack2_bf16(b[2], b[3]);
            xf[ks] = cv.v;
        }

        floatx4 acc[8];
#pragma unroll
        for (int ct = 0; ct < 8; ++ct) acc[ct] = (floatx4)0.0f;

#pragma unroll
        for (int ks = 0; ks < 4; ++ks) {
            const int ko = ks * 32 + quad * 8;
#pragma unroll
            for (int ct = 0; ct < 8; ++ct) {
                const shortx8 mf = *(const shortx8*)(&Msh[(ct*16 + l15) * 136 + ko]);
                acc[ct] = __builtin_amdgcn_mfma_f32_16x16x32_bf16(mf, xf[ks], acc[ct], 0, 0, 0);
            }
        }

        // epilogue: per-wave LDS transpose, two 64-d halves, contiguous stores.
        // Same-wave DS ops are processed in order -> no barrier needed.
        float* yt = y + base + (size_t)(row0 + t * 16) * 128;
#pragma unroll
        for (int dh = 0; dh < 2; ++dh) {
#pragma unroll
            for (int c = 0; c < 4; ++c)
                *(floatx4*)(&ob[l15 * 68 + c * 16 + quad * 4]) = acc[dh*4 + c];
#pragma unroll
            for (int j = 0; j < 4; ++j) {
                const int f   = j * 256 + lane * 4;   // 0..1023 within half
                const int r   = f >> 6;               // row 0..15
                const int col = f & 63;               // d within half
                const floatx4 v = *(const floatx4*)(&ob[r * 68 + col]);
                __builtin_nontemporal_store(v, (floatx4*)(yt + (size_t)r * 128 + dh * 64 + col));
            }
        }
    }
}

extern "C" void kernel_launch(void* const* d_in, const int* in_sizes, int n_in,
                              void* d_out, int out_size, void* d_ws, size_t ws_size,
                              hipStream_t stream) {
    const float* x     = (const float*)d_in[0];   // (4,16,4096,128) fp32
    const float* S_raw = (const float*)d_in[1];   // (16,128,128) fp32
    float* y = (float*)d_out;                     // (4,16,4096,128) fp32
    unsigned short* Mb = (unsigned short*)d_ws;   // 16*128*128 bf16 = 512 KB

    cayley_invert<<<16, 512, 0, stream>>>(S_raw, Mb);
    cayley_apply<<<64 * 8, 256, 0, stream>>>(x, Mb, y);
}